// Round 11
// baseline (196.312 us; speedup 1.0000x reference)
//
#include <hip/hip_runtime.h>

// Problem constants (fixed by setup_inputs).
#define B_     16
#define C_     3
#define H_     512
#define W_     1024
#define MW     256         // mask_width
#define RS     16          // output rows per strip
#define NSTRIP 32          // 32*16 = 512 exact
#define NIN    (RS + 10)   // 26 input rows streamed per strip
#define NBLK   (B_ * C_ * NSTRIP)  // 1536

typedef const __attribute__((address_space(1))) void gvoid;
typedef __attribute__((address_space(3))) void lvoid;

#define GLDS(g, l) __builtin_amdgcn_global_load_lds((gvoid*)(g), (lvoid*)(l), 4, 0, 0)
#define WAITV(N)   asm volatile("s_waitcnt vmcnt(" #N ")" ::: "memory")

__global__ __launch_bounds__(256) void ssim_main(const float* __restrict__ img1,
                                                 const float* __restrict__ img2,
                                                 const int*   __restrict__ mask_pos,
                                                 float*        __restrict__ accum,
                                                 unsigned int* __restrict__ cnt,
                                                 float*        __restrict__ out,
                                                 const float*  __restrict__ zp) {
    constexpr float G[11] = {
        0.00102838f, 0.00759876f, 0.03600077f, 0.10936070f, 0.21300553f,
        0.26601173f, 0.21300553f, 0.10936070f, 0.03600077f, 0.00759876f,
        0.00102838f };

    // Ring of 5 per-wave buffers, 2 raw planes (a,b), 136 floats each.
    // DMA (global_load_lds) writes them; ds_reads consume 3 iterations later.
    __shared__ float ring[4][5][2][136];
    __shared__ float blksum[4];

    const int tid  = threadIdx.x;
    const int w    = tid >> 6;
    const int lane = tid & 63;

    // XCD L2-locality remap (8 XCDs x 6 images x 32 strips; bijection).
    const int d     = blockIdx.x;
    const int xcd   = d & 7;
    const int q     = d >> 3;
    const int bc    = xcd * 6 + (q >> 5);
    const int strip = q & 31;
    const int b     = bc / 3;

    int s0 = mask_pos[b];
    s0 = min(max(s0, 0), W_ - MW);

    const float* __restrict__ p1 = img1 + (size_t)bc * (H_ * W_);
    const float* __restrict__ p2 = img2 + (size_t)bc * (H_ * W_);

    const int y0  = strip * RS;
    const int sx0 = w << 6;

    // Main 64-lane load: w=0 loads cols 0..63 into buf[5..68] (left pad LDS-
    // zeroed once); w>0 loads cols sx0-5..sx0+58 into buf[0..63].
    const int gco = (w == 0) ? 0 : (sx0 - 5);   // + lane -> crop col (always valid)
    const int dco = (w == 0) ? 5 : 0;           // LDS dest base
    // Halo 64-lane load: dest buf[dco+64]; lanes whose crop col >= MW (and the
    // garbage lanes landing in buf[74+]) read real neighbor cols when valid.
    const int hco = sx0 + ((w == 0) ? 64 : 59); // + lane -> crop col

    const int mo = s0 + gco + lane;             // global col, main
    const int hc = hco + lane;                  // crop col, halo
    const bool hv = hc < MW;
    const int ho = s0 + hc;

    auto issue_row = [&](int r, int slot) {
        const bool rok = (r >= 0) && (r < H_);  // wave-uniform
        const int ro = r * W_;
        const float* pa  = rok ? (p1 + ro + mo) : zp;
        const float* pb  = rok ? (p2 + ro + mo) : zp;
        const float* pha = (rok && hv) ? (p1 + ro + ho) : zp;
        const float* phb = (rok && hv) ? (p2 + ro + ho) : zp;
        GLDS(pa,  &ring[w][slot][0][dco]);
        GLDS(pha, &ring[w][slot][0][dco + 64]);
        GLDS(pb,  &ring[w][slot][1][dco]);
        GLDS(phb, &ring[w][slot][1][dco + 64]);
    };

    // 11 pending output rows x 4 fields {mu_p, mu_m, Suu, Svv}; static slots.
    float acc[11][4];
    #pragma unroll
    for (int s = 0; s < 11; ++s)
        #pragma unroll
        for (int f = 0; f < 4; ++f) acc[s][f] = 0.f;

    float psum = 0.f;
    int rd = 0, wr = 3;                         // ring read / write cursors

    // w=0 left pad: buf[0..4] of both planes, all 5 slots, zero once.
    if (w == 0 && lane < 5) {
        #pragma unroll
        for (int sl5 = 0; sl5 < 5; ++sl5) {
            ring[0][sl5][0][lane] = 0.f;
            ring[0][sl5][1][lane] = 0.f;
        }
    }

    // Prologue: issue rows 0,1,2 (12 loads outstanding).
    issue_row(y0 - 5, 0);
    issue_row(y0 - 4, 1);
    issue_row(y0 - 3, 2);

    auto dorow = [&](int i, int sl, int wn) {
        // Counted wait: row i's 4 DMAs complete; 8 newer stay in flight.
        if (wn == 8)      WAITV(8);
        else if (wn == 4) WAITV(4);
        else              WAITV(0);
        // Issue row i+3 (consumed 3 iterations from now: ~1000 cyc cover).
        if (i + 3 < NIN) {
            issue_row(y0 - 2 + i, wr);
            wr = (wr == 4) ? 0 : wr + 1;
        }

        // Horizontal 11-tap pass on raw planes; u/v transform on the fly.
        float su = 0.f, sv = 0.f, suu = 0.f, svv = 0.f;
        #pragma unroll
        for (int t = 0; t < 11; ++t) {
            const float a = ring[w][rd][0][lane + t];
            const float bb = ring[w][rd][1][lane + t];
            const float u = a + bb, v = a - bb;
            const float gu = G[t] * u;
            const float gv = G[t] * v;
            su += gu;
            sv += gv;
            suu = fmaf(gu, u, suu);
            svv = fmaf(gv, v, svv);
        }
        rd = (rd == 4) ? 0 : rd + 1;

        // Vertical accumulation into the 11 pending outputs (static slots).
        #pragma unroll
        for (int m = 0; m < 11; ++m) {
            const int s = (sl + m) % 11;
            const float gw = G[10 - m];
            acc[s][0] = fmaf(gw, su,  acc[s][0]);
            acc[s][1] = fmaf(gw, sv,  acc[s][1]);
            acc[s][2] = fmaf(gw, suu, acc[s][2]);
            acc[s][3] = fmaf(gw, svv, acc[s][3]);
        }

        // Output row completes in slot sl at i >= 10.
        if (i >= 10) {
            const float mup = acc[sl][0], mum = acc[sl][1];
            const float Suu = acc[sl][2], Svv = acc[sl][3];
            const float A  = mup * mup, Bq = mum * mum;
            const float mu_sq_sum = 0.5f * (A + Bq);
            const float mu_cross2 = 0.5f * (A - Bq);
            const float e_sum     = 0.5f * (Suu + Svv);
            const float e_cross2  = 0.5f * (Suu - Svv);
            const float sig_sum = e_sum - mu_sq_sum;
            const float sig12_2 = e_cross2 - mu_cross2;
            const float num = (mu_cross2 + 1e-4f) * (sig12_2 + 9e-4f) + 1e-5f;
            const float den = (mu_sq_sum + 1e-4f) * (sig_sum + 9e-4f) + 1e-5f;
            psum += __fdividef(num, den);
        }
        #pragma unroll
        for (int f = 0; f < 4; ++f) acc[sl][f] = 0.f;
    };

    // Main 22 rows (2 x 11, sl static), then 4-row tail with draining waits.
    for (int ii = 0; ii < 22; ii += 11) {
        #pragma unroll
        for (int j = 0; j < 11; ++j) dorow(ii + j, j, 8);
    }
    dorow(22, 0, 8);
    dorow(23, 1, 8);
    dorow(24, 2, 4);
    dorow(25, 3, 0);

    // Wave reduce -> block reduce -> one atomic; last block finalizes.
    #pragma unroll
    for (int off = 32; off > 0; off >>= 1) psum += __shfl_xor(psum, off, 64);
    if (lane == 0) blksum[w] = psum;
    __syncthreads();
    if (tid == 0) {
        atomicAdd(accum, blksum[0] + blksum[1] + blksum[2] + blksum[3]);
        __threadfence();
        const unsigned int done = atomicAdd(cnt, 1u);
        if (done == NBLK - 1) {
            const float tot = atomicAdd(accum, 0.f);  // device-scope read
            out[0] = 1.0f - tot * (1.0f / 6291456.0f); // B*C*H*MW
        }
    }
}

extern "C" void kernel_launch(void* const* d_in, const int* in_sizes, int n_in,
                              void* d_out, int out_size, void* d_ws, size_t ws_size,
                              hipStream_t stream) {
    const float* img1 = (const float*)d_in[0];
    const float* img2 = (const float*)d_in[1];
    const int*   pos  = (const int*)d_in[2];
    float*        acc = (float*)d_ws;                          // +0
    unsigned int* cnt = (unsigned int*)((char*)d_ws + 4);      // +4
    const float*  zp  = (const float*)((char*)d_ws + 64);      // zero page

    hipMemsetAsync(d_ws, 0, 128, stream);   // zeroes accum, cnt, zero page

    ssim_main<<<NBLK, 256, 0, stream>>>(img1, img2, pos, acc, cnt,
                                        (float*)d_out, zp);
}

// Round 12
// 129.380 us; speedup vs baseline: 1.5173x; 1.5173x over previous
//
#include <hip/hip_runtime.h>

// Problem constants (fixed by setup_inputs).
#define B_     16
#define C_     3
#define H_     512
#define W_     1024
#define MW     256         // mask_width
#define RS     16          // output rows per strip
#define NSTRIP 32          // 32*16 = 512 exact
#define NIN    (RS + 10)   // 26 input rows streamed per strip
#define NBLK   (B_ * C_ * NSTRIP)  // 1536

// Memory fence only: wave_barrier pins DS/VMEM ordering but lets pure VALU
// flow across iterations (software pipelining). Proven in rounds 9-10.
#define FENCE() __builtin_amdgcn_wave_barrier()

__global__ __launch_bounds__(256) void ssim_main(const float* __restrict__ img1,
                                                 const float* __restrict__ img2,
                                                 const int*   __restrict__ mask_pos,
                                                 float*        __restrict__ accum,
                                                 unsigned int* __restrict__ cnt,
                                                 float*        __restrict__ out) {
    // Gaussian weights = float64 exp/normalize, precomputed to float literals.
    constexpr float G[11] = {
        0.00102838f, 0.00759876f, 0.03600077f, 0.10936070f, 0.21300553f,
        0.26601173f, 0.21300553f, 0.10936070f, 0.03600077f, 0.00759876f,
        0.00102838f };

    // Per-wave double-buffered 74-col {u=x+y, v=x-y} row ring. ~5 KB total.
    // Row i lives in LDS buffer (i&1).
    __shared__ float2 rowbuf[4][2][80];
    __shared__ float  blksum[4];

    const int tid  = threadIdx.x;
    const int w    = tid >> 6;
    const int lane = tid & 63;

    // XCD L2-locality remap (8 XCDs x 6 images x 32 strips; bijection).
    const int d     = blockIdx.x;
    const int xcd   = d & 7;
    const int q     = d >> 3;            // 0..191 within XCD
    const int bc    = xcd * 6 + (q >> 5);// (b,ch) 0..47
    const int strip = q & 31;            // row strip 0..31
    const int b     = bc / 3;

    int s0 = mask_pos[b];
    s0 = min(max(s0, 0), W_ - MW);

    const float* __restrict__ p1 = img1 + (size_t)bc * (H_ * W_);
    const float* __restrict__ p2 = img2 + (size_t)bc * (H_ * W_);

    const int y0  = strip * RS;
    const int sx0 = w << 6;              // column strip base within crop
    const int cxm = sx0 - 5 + lane;      // main staged column (crop coords)
    const int cxh = sx0 + 59 + lane;     // halo staged column (lane < 10)
    const bool vm = (cxm >= 0) && (cxm < MW);
    const bool vh = (lane < 10) && (cxh < MW);
    const int gxm = s0 + cxm;
    const int gxh = s0 + cxh;

    // TWO named prefetch register sets (distance-2 pipeline): row r is loaded
    // at iter r-2 into set r&1, stored to LDS buf r&1 at iter r-1, read at
    // iter r. Issue-to-consume spans ~2 iteration bodies of compute; the
    // compiler's counted vmcnt(4) keeps the newer set's loads in flight.
    float Aa0, Ab0, Aa1, Ab1;            // set 0 (even rows)
    float Ba0, Bb0, Ba1, Bb1;            // set 1 (odd rows)

    auto loadA = [&](int r) {
        Aa0 = Ab0 = Aa1 = Ab1 = 0.f;
        if (r >= 0 && r < H_) {          // wave-uniform branch
            const int ro = r * W_;
            if (vm) { Aa0 = p1[ro + gxm]; Ab0 = p2[ro + gxm]; }
            if (vh) { Aa1 = p1[ro + gxh]; Ab1 = p2[ro + gxh]; }
        }
    };
    auto loadB = [&](int r) {
        Ba0 = Bb0 = Ba1 = Bb1 = 0.f;
        if (r >= 0 && r < H_) {
            const int ro = r * W_;
            if (vm) { Ba0 = p1[ro + gxm]; Bb0 = p2[ro + gxm]; }
            if (vh) { Ba1 = p1[ro + gxh]; Bb1 = p2[ro + gxh]; }
        }
    };
    // u/v transform INLINE at the store (round-8 lesson: first use of the
    // loads — and thus the vmcnt wait — belongs at the ds_write).
    auto storeA = [&]() {                // even rows -> LDS buf 0
        rowbuf[w][0][lane] = make_float2(Aa0 + Ab0, Aa0 - Ab0);
        if (lane < 10) rowbuf[w][0][64 + lane] = make_float2(Aa1 + Ab1, Aa1 - Ab1);
    };
    auto storeB = [&]() {                // odd rows -> LDS buf 1
        rowbuf[w][1][lane] = make_float2(Ba0 + Bb0, Ba0 - Bb0);
        if (lane < 10) rowbuf[w][1][64 + lane] = make_float2(Ba1 + Bb1, Ba1 - Bb1);
    };

    // 11 pending output rows x 4 conv fields {mu_p, mu_m, Suu, Svv};
    // slot index sl and LDS parity par are compile-time at every call site.
    float acc[11][4];
    #pragma unroll
    for (int s = 0; s < 11; ++s)
        #pragma unroll
        for (int f = 0; f < 4; ++f) acc[s][f] = 0.f;

    float psum = 0.f;

    auto dorow = [&](int i, int sl, int par) {
        // Issue row i+2 into set par (== (i+2)&1). Its old contents (row i)
        // were consumed by the ds_write at the end of iter i-1.
        if (i + 2 < NIN) {
            if (par == 0) loadA(y0 - 3 + i);   // (y0-5) + (i+2)
            else          loadB(y0 - 3 + i);
        }

        // Horizontal 11-tap pass over 4 fields from LDS buffer par.
        float su = 0.f, sv = 0.f, suu = 0.f, svv = 0.f;
        #pragma unroll
        for (int t = 0; t < 11; ++t) {
            const float2 q2 = rowbuf[w][par][lane + t];
            const float gu = G[t] * q2.x;
            const float gv = G[t] * q2.y;
            su += gu;
            sv += gv;
            suu = fmaf(gu, q2.x, suu);
            svv = fmaf(gv, q2.y, svv);
        }

        // Vertical accumulation into the 11 pending outputs (static slots).
        #pragma unroll
        for (int m = 0; m < 11; ++m) {
            const int s = (sl + m) % 11;
            const float gw = G[10 - m];
            acc[s][0] = fmaf(gw, su,  acc[s][0]);
            acc[s][1] = fmaf(gw, sv,  acc[s][1]);
            acc[s][2] = fmaf(gw, suu, acc[s][2]);
            acc[s][3] = fmaf(gw, svv, acc[s][3]);
        }

        // Output row o = y0 + i - 10 completes in slot sl at i >= 10.
        if (i >= 10) {
            const float mup = acc[sl][0], mum = acc[sl][1];
            const float Suu = acc[sl][2], Svv = acc[sl][3];
            const float A  = mup * mup, Bq = mum * mum;
            const float mu_sq_sum = 0.5f * (A + Bq);    // mu1^2 + mu2^2
            const float mu_cross2 = 0.5f * (A - Bq);    // 2*mu1*mu2
            const float e_sum     = 0.5f * (Suu + Svv); // Exx + Eyy
            const float e_cross2  = 0.5f * (Suu - Svv); // 2*Exy
            const float sig_sum = e_sum - mu_sq_sum;    // sig1 + sig2
            const float sig12_2 = e_cross2 - mu_cross2; // 2*sig12
            const float num = (mu_cross2 + 1e-4f) * (sig12_2 + 9e-4f) + 1e-5f;
            const float den = (mu_sq_sum + 1e-4f) * (sig_sum + 9e-4f) + 1e-5f;
            psum += __fdividef(num, den);
        }
        // Slot sl recycled: always reset.
        #pragma unroll
        for (int f = 0; f < 4; ++f) acc[sl][f] = 0.f;

        // Store row i+1 (set par^1, loaded one full iteration ago) into LDS
        // buf par^1. The vmcnt wait here covers ~2 iteration bodies.
        if (i + 1 < NIN) {
            if (par == 0) storeB();
            else          storeA();
        }
        // Memory-only fence: DS/VMEM may not cross; VALU may.
        FENCE();
    };

    // Prologue: row 0 -> set0 -> LDS buf0; row 1 -> set1 (held in regs).
    loadA(y0 - 5);
    loadB(y0 - 4);
    storeA();
    FENCE();

    // 22-row main (lcm(2,11): slot and parity both compile-time), 4-row tail
    // (22%11 == 0 and 22 even, so tail slot=j, parity=j&1).
    #pragma unroll
    for (int j = 0; j < 22; ++j) dorow(j, j % 11, j & 1);
    #pragma unroll
    for (int j = 0; j < 4; ++j) dorow(22 + j, j, j & 1);

    // Wave reduce -> block reduce -> one atomic; last block finalizes.
    #pragma unroll
    for (int off = 32; off > 0; off >>= 1) psum += __shfl_xor(psum, off, 64);
    if (lane == 0) blksum[w] = psum;
    __syncthreads();
    if (tid == 0) {
        atomicAdd(accum, blksum[0] + blksum[1] + blksum[2] + blksum[3]);
        __threadfence();
        const unsigned int done = atomicAdd(cnt, 1u);
        if (done == NBLK - 1) {
            const float tot = atomicAdd(accum, 0.f);   // device-scope read
            out[0] = 1.0f - tot * (1.0f / 6291456.0f); // B*C*H*MW
        }
    }
}

extern "C" void kernel_launch(void* const* d_in, const int* in_sizes, int n_in,
                              void* d_out, int out_size, void* d_ws, size_t ws_size,
                              hipStream_t stream) {
    const float* img1 = (const float*)d_in[0];
    const float* img2 = (const float*)d_in[1];
    const int*   pos  = (const int*)d_in[2];
    float*        acc = (float*)d_ws;                     // +0
    unsigned int* cnt = (unsigned int*)((char*)d_ws + 4); // +4

    hipMemsetAsync(d_ws, 0, 8, stream);

    // 8 XCDs x 6 images x 32 strips; each block = 4 waves = 4 column strips.
    ssim_main<<<NBLK, 256, 0, stream>>>(img1, img2, pos, acc, cnt,
                                        (float*)d_out);
}

// Round 13
// 123.730 us; speedup vs baseline: 1.5866x; 1.0457x over previous
//
#include <hip/hip_runtime.h>

// Problem constants (fixed by setup_inputs).
#define B_     16
#define C_     3
#define H_     512
#define W_     1024
#define MW     256         // mask_width
#define RS     16          // output rows per strip
#define NSTRIP 32          // 32*16 = 512 exact
#define NIN    (RS + 10)   // 26 input rows streamed per strip
#define NBLK   (B_ * C_ * NSTRIP)  // 1536

// Memory fence only: wave_barrier pins DS/VMEM ordering but lets pure VALU
// flow across iterations (software pipelining). Proven rounds 9-10.
#define FENCE() __builtin_amdgcn_wave_barrier()

__global__ __launch_bounds__(256) void ssim_main(const float* __restrict__ img1,
                                                 const float* __restrict__ img2,
                                                 const int*   __restrict__ mask_pos,
                                                 float*        __restrict__ accum,
                                                 unsigned int* __restrict__ cnt,
                                                 float*        __restrict__ out) {
    // Gaussian weights = float64 exp/normalize, precomputed to float literals.
    constexpr float G[11] = {
        0.00102838f, 0.00759876f, 0.03600077f, 0.10936070f, 0.21300553f,
        0.26601173f, 0.21300553f, 0.10936070f, 0.03600077f, 0.00759876f,
        0.00102838f };

    // Per-wave double-buffered 74-col {u=x+y, v=x-y} row ring. ~5 KB total.
    __shared__ float2 rowbuf[4][2][80];
    __shared__ float  blksum[4];

    const int tid  = threadIdx.x;
    const int w    = tid >> 6;
    const int lane = tid & 63;

    // XCD L2-locality remap (8 XCDs x 6 images x 32 strips; bijection).
    const int d     = blockIdx.x;
    const int xcd   = d & 7;
    const int q     = d >> 3;            // 0..191 within XCD
    const int bc    = xcd * 6 + (q >> 5);// (b,ch) 0..47
    const int strip = q & 31;            // row strip 0..31
    const int b     = bc / 3;

    int s0 = mask_pos[b];
    s0 = min(max(s0, 0), W_ - MW);

    const float* __restrict__ p1 = img1 + (size_t)bc * (H_ * W_);
    const float* __restrict__ p2 = img2 + (size_t)bc * (H_ * W_);

    const int y0  = strip * RS;
    const int sx0 = w << 6;              // column strip base within crop
    const int cxm = sx0 - 5 + lane;      // main staged column (crop coords)
    const int cxh = sx0 + 59 + lane;     // halo staged column (lane < 10)
    const bool vm = (cxm >= 0) && (cxm < MW);
    const bool vh = (lane < 10) && (cxh < MW);
    const int gxm = s0 + cxm;
    const int gxh = s0 + cxh;

    // Single in-flight prefetch register set (distance 1) — RAW values only.
    // u/v transform happens AT THE STORE (bottom of iteration) so the vmcnt
    // wait stays at the ds_write, hidden under this row's compute (round 8).
    float pa0, pb0, pa1, pb1;
    auto loadrow = [&](int r) {
        pa0 = pb0 = pa1 = pb1 = 0.f;
        if (r >= 0 && r < H_) {          // wave-uniform branch
            const int ro = r * W_;
            if (vm) { pa0 = p1[ro + gxm]; pb0 = p2[ro + gxm]; }
            if (vh) { pa1 = p1[ro + gxh]; pb1 = p2[ro + gxh]; }
        }
    };

    // Sliding window of the last 11 h-pass results x 4 fields
    // {su, sv, suu, svv}. GATHER form: the 44-FMA weighted reduction runs
    // only on output-producing iterations (16 of 26) instead of scattering
    // 44 FMAs on every input row. Same 44-VGPR footprint as the old acc[].
    float h[11][4];

    float psum = 0.f;
    int cur = 0;                         // runtime LDS parity (LDS, not VGPR array)

    auto dorow = [&](int i, int sl) {
        const bool notlast = (i + 1 < NIN);

        // Prefetch row i+1 into registers (hidden under this row's math).
        if (notlast) loadrow(y0 - 4 + i);

        // Horizontal 11-tap pass over 4 fields from LDS buffer `cur`.
        float su = 0.f, sv = 0.f, suu = 0.f, svv = 0.f;
        #pragma unroll
        for (int t = 0; t < 11; ++t) {
            const float2 q2 = rowbuf[w][cur][lane + t];
            const float gu = G[t] * q2.x;
            const float gv = G[t] * q2.y;
            su += gu;
            sv += gv;
            suu = fmaf(gu, q2.x, suu);
            svv = fmaf(gv, q2.y, svv);
        }

        // Write this row's h-results into ring slot sl (overwrites the row
        // that just aged out of all output windows).
        h[sl][0] = su; h[sl][1] = sv; h[sl][2] = suu; h[sl][3] = svv;

        // Output row o = y0 + i - 10 completes at i >= 10: gather the 11
        // window rows. Row from iter i-k has weight G[10-k], slot (sl-k)%11.
        if (i >= 10) {
            float mup = 0.f, mum = 0.f, Suu = 0.f, Svv = 0.f;
            #pragma unroll
            for (int k = 0; k < 11; ++k) {
                const int s = (sl - k + 11) % 11;
                const float gw = G[10 - k];
                mup = fmaf(gw, h[s][0], mup);
                mum = fmaf(gw, h[s][1], mum);
                Suu = fmaf(gw, h[s][2], Suu);
                Svv = fmaf(gw, h[s][3], Svv);
            }
            const float A  = mup * mup, Bq = mum * mum;
            const float mu_sq_sum = 0.5f * (A + Bq);    // mu1^2 + mu2^2
            const float mu_cross2 = 0.5f * (A - Bq);    // 2*mu1*mu2
            const float e_sum     = 0.5f * (Suu + Svv); // Exx + Eyy
            const float e_cross2  = 0.5f * (Suu - Svv); // 2*Exy
            const float sig_sum = e_sum - mu_sq_sum;    // sig1 + sig2
            const float sig12_2 = e_cross2 - mu_cross2; // 2*sig12
            const float num = (mu_cross2 + 1e-4f) * (sig12_2 + 9e-4f) + 1e-5f;
            const float den = (mu_sq_sum + 1e-4f) * (sig_sum + 9e-4f) + 1e-5f;
            psum += __fdividef(num, den);
        }

        // Stage prefetched row i+1: u/v computed INLINE at the store, so the
        // first use of the loads (and the vmcnt wait) is here.
        if (notlast) {
            rowbuf[w][cur ^ 1][lane] = make_float2(pa0 + pb0, pa0 - pb0);
            if (lane < 10)
                rowbuf[w][cur ^ 1][64 + lane] = make_float2(pa1 + pb1, pa1 - pb1);
        }
        cur ^= 1;
        // Memory-only fence: DS/VMEM may not cross; VALU may.
        FENCE();
    };

    // Prologue: stage streamed row 0 (input row y0-5) into parity 0.
    loadrow(y0 - 5);
    rowbuf[w][0][lane] = make_float2(pa0 + pb0, pa0 - pb0);
    if (lane < 10) rowbuf[w][0][64 + lane] = make_float2(pa1 + pb1, pa1 - pb1);
    FENCE();

    // Main 22 rows (2 x 11 so sl stays compile-time; do NOT unroll deeper —
    // rounds 4/6/12 proved >11-deep fenced unrolls spill), then 4-row tail
    // (22 % 11 == 0, so tail slot == j, still compile-time).
    for (int ii = 0; ii < 22; ii += 11) {
        #pragma unroll
        for (int j = 0; j < 11; ++j) dorow(ii + j, j);
    }
    #pragma unroll
    for (int j = 0; j < 4; ++j) dorow(22 + j, j);

    // Wave reduce -> block reduce -> one atomic; last block finalizes.
    #pragma unroll
    for (int off = 32; off > 0; off >>= 1) psum += __shfl_xor(psum, off, 64);
    if (lane == 0) blksum[w] = psum;
    __syncthreads();
    if (tid == 0) {
        atomicAdd(accum, blksum[0] + blksum[1] + blksum[2] + blksum[3]);
        __threadfence();
        const unsigned int done = atomicAdd(cnt, 1u);
        if (done == NBLK - 1) {
            const float tot = atomicAdd(accum, 0.f);   // device-scope read
            out[0] = 1.0f - tot * (1.0f / 6291456.0f); // B*C*H*MW
        }
    }
}

extern "C" void kernel_launch(void* const* d_in, const int* in_sizes, int n_in,
                              void* d_out, int out_size, void* d_ws, size_t ws_size,
                              hipStream_t stream) {
    const float* img1 = (const float*)d_in[0];
    const float* img2 = (const float*)d_in[1];
    const int*   pos  = (const int*)d_in[2];
    float*        acc = (float*)d_ws;                     // +0
    unsigned int* cnt = (unsigned int*)((char*)d_ws + 4); // +4

    hipMemsetAsync(d_ws, 0, 8, stream);

    // 8 XCDs x 6 images x 32 strips; each block = 4 waves = 4 column strips.
    ssim_main<<<NBLK, 256, 0, stream>>>(img1, img2, pos, acc, cnt,
                                        (float*)d_out);
}

// Round 14
// 75.086 us; speedup vs baseline: 2.6145x; 1.6479x over previous
//
#include <hip/hip_runtime.h>

// Problem constants (fixed by setup_inputs).
#define B_     16
#define C_     3
#define H_     512
#define W_     1024
#define MW     256         // mask_width
#define RS     16          // output rows per strip
#define NSTRIP 32          // 32*16 = 512 exact
#define NIN    (RS + 10)   // 26 input rows streamed per strip
#define NBLK   (B_ * C_ * NSTRIP)  // 1536

// Memory fence only: wave_barrier pins all DS/VMEM ordering (IR + MIR) but
// lets pure VALU flow across iterations (software pipelining).
#define FENCE() __builtin_amdgcn_wave_barrier()

__global__ __launch_bounds__(256) void ssim_main(const float* __restrict__ img1,
                                                 const float* __restrict__ img2,
                                                 const int*   __restrict__ mask_pos,
                                                 float*        __restrict__ accum,
                                                 unsigned int* __restrict__ cnt,
                                                 float*        __restrict__ out) {
    // Gaussian weights = float64 exp/normalize, precomputed to float literals.
    constexpr float G[11] = {
        0.00102838f, 0.00759876f, 0.03600077f, 0.10936070f, 0.21300553f,
        0.26601173f, 0.21300553f, 0.10936070f, 0.03600077f, 0.00759876f,
        0.00102838f };

    // Per-wave double-buffered 74-col {u=x+y, v=x-y} row ring. ~5 KB total.
    __shared__ float2 rowbuf[4][2][80];
    __shared__ float  blksum[4];

    const int tid  = threadIdx.x;
    const int w    = tid >> 6;
    const int lane = tid & 63;

    // XCD L2-locality remap (8 XCDs x 6 images x 32 strips; bijection).
    const int d     = blockIdx.x;
    const int xcd   = d & 7;
    const int q     = d >> 3;            // 0..191 within XCD
    const int bc    = xcd * 6 + (q >> 5);// (b,ch) 0..47
    const int strip = q & 31;            // row strip 0..31
    const int b     = bc / 3;

    int s0 = mask_pos[b];
    s0 = min(max(s0, 0), W_ - MW);

    const float* __restrict__ p1 = img1 + (size_t)bc * (H_ * W_);
    const float* __restrict__ p2 = img2 + (size_t)bc * (H_ * W_);

    const int y0  = strip * RS;
    const int sx0 = w << 6;              // column strip base within crop
    const int cxm = sx0 - 5 + lane;      // main staged column (crop coords)
    const int cxh = sx0 + 59 + lane;     // halo staged column (lane < 10)
    const bool vm = (cxm >= 0) && (cxm < MW);
    const bool vh = (lane < 10) && (cxh < MW);
    const int gxm = s0 + cxm;
    const int gxh = s0 + cxh;

    // Single in-flight prefetch register set (distance 1) — RAW values only.
    // u/v transform happens AT THE STORE (bottom of iteration) so the vmcnt
    // wait stays at the ds_write, hidden under this row's compute.
    float pa0, pb0, pa1, pb1;
    auto loadrow = [&](int r) {
        pa0 = pb0 = pa1 = pb1 = 0.f;
        if (r >= 0 && r < H_) {          // wave-uniform branch
            const int ro = r * W_;
            if (vm) { pa0 = p1[ro + gxm]; pb0 = p2[ro + gxm]; }
            if (vh) { pa1 = p1[ro + gxh]; pb1 = p2[ro + gxh]; }
        }
    };

    // 11 pending output rows x 4 conv fields {mu_p, mu_m, Suu, Svv};
    // slot index `sl` is compile-time at every call site. SCATTER-RMW form:
    // the serialized accumulator chains constrain the scheduler — this is
    // load-bearing for regalloc (gather form spilled to 256 VGPR, round 13).
    float acc[11][4];
    #pragma unroll
    for (int s = 0; s < 11; ++s)
        #pragma unroll
        for (int f = 0; f < 4; ++f) acc[s][f] = 0.f;

    float psum = 0.f;
    int cur = 0;                         // runtime LDS parity (LDS, not VGPR array)

    auto dorow = [&](int i, int sl) {
        const bool notlast = (i + 1 < NIN);

        // Prefetch row i+1 into registers (hidden under this row's math).
        if (notlast) loadrow(y0 - 4 + i);

        // Horizontal 11-tap pass over 4 fields from LDS buffer `cur`.
        float su = 0.f, sv = 0.f, suu = 0.f, svv = 0.f;
        #pragma unroll
        for (int t = 0; t < 11; ++t) {
            const float2 q2 = rowbuf[w][cur][lane + t];
            const float gu = G[t] * q2.x;
            const float gv = G[t] * q2.y;
            su += gu;
            sv += gv;
            suu = fmaf(gu, q2.x, suu);
            svv = fmaf(gv, q2.y, svv);
        }

        // Vertical accumulation into the 11 pending outputs (static slots).
        #pragma unroll
        for (int m = 0; m < 11; ++m) {
            const int s = (sl + m) % 11;
            const float gw = G[10 - m];
            acc[s][0] = fmaf(gw, su,  acc[s][0]);
            acc[s][1] = fmaf(gw, sv,  acc[s][1]);
            acc[s][2] = fmaf(gw, suu, acc[s][2]);
            acc[s][3] = fmaf(gw, svv, acc[s][3]);
        }

        // Output row o = y0 + i - 10 completes in slot sl at i >= 10.
        if (i >= 10) {
            const float mup = acc[sl][0], mum = acc[sl][1];
            const float Suu = acc[sl][2], Svv = acc[sl][3];
            const float A  = mup * mup, Bq = mum * mum;
            const float mu_sq_sum = 0.5f * (A + Bq);    // mu1^2 + mu2^2
            const float mu_cross2 = 0.5f * (A - Bq);    // 2*mu1*mu2
            const float e_sum     = 0.5f * (Suu + Svv); // Exx + Eyy
            const float e_cross2  = 0.5f * (Suu - Svv); // 2*Exy
            const float sig_sum = e_sum - mu_sq_sum;    // sig1 + sig2
            const float sig12_2 = e_cross2 - mu_cross2; // 2*sig12
            const float num = (mu_cross2 + 1e-4f) * (sig12_2 + 9e-4f) + 1e-5f;
            const float den = (mu_sq_sum + 1e-4f) * (sig_sum + 9e-4f) + 1e-5f;
            psum += __fdividef(num, den);
        }
        // Slot sl recycled: always reset.
        #pragma unroll
        for (int f = 0; f < 4; ++f) acc[sl][f] = 0.f;

        // Stage prefetched row i+1: u/v computed INLINE at the store, so the
        // first use of the loads (and the vmcnt wait) is here.
        if (notlast) {
            rowbuf[w][cur ^ 1][lane] = make_float2(pa0 + pb0, pa0 - pb0);
            if (lane < 10)
                rowbuf[w][cur ^ 1][64 + lane] = make_float2(pa1 + pb1, pa1 - pb1);
        }
        cur ^= 1;
        // Memory-only fence: DS/VMEM may not cross; VALU may.
        FENCE();
    };

    // Prologue: stage streamed row 0 (input row y0-5) into parity 0.
    loadrow(y0 - 5);
    rowbuf[w][0][lane] = make_float2(pa0 + pb0, pa0 - pb0);
    if (lane < 10) rowbuf[w][0][64 + lane] = make_float2(pa1 + pb1, pa1 - pb1);
    FENCE();

    // Main 22 rows (2 x 11 so sl stays compile-time; do NOT unroll deeper —
    // rounds 4/6/12 proved >11-deep fenced unrolls spill), then 4-row tail
    // (22 % 11 == 0, so tail slot == j, still compile-time).
    for (int ii = 0; ii < 22; ii += 11) {
        #pragma unroll
        for (int j = 0; j < 11; ++j) dorow(ii + j, j);
    }
    #pragma unroll
    for (int j = 0; j < 4; ++j) dorow(22 + j, j);

    // Wave reduce -> block reduce -> one atomic; last block finalizes
    // (outside the fenced loop: cannot perturb its scheduling).
    #pragma unroll
    for (int off = 32; off > 0; off >>= 1) psum += __shfl_xor(psum, off, 64);
    if (lane == 0) blksum[w] = psum;
    __syncthreads();
    if (tid == 0) {
        atomicAdd(accum, blksum[0] + blksum[1] + blksum[2] + blksum[3]);
        __threadfence();
        const unsigned int done = atomicAdd(cnt, 1u);
        if (done == NBLK - 1) {
            const float tot = atomicAdd(accum, 0.f);   // device-scope read
            out[0] = 1.0f - tot * (1.0f / 6291456.0f); // B*C*H*MW
        }
    }
}

extern "C" void kernel_launch(void* const* d_in, const int* in_sizes, int n_in,
                              void* d_out, int out_size, void* d_ws, size_t ws_size,
                              hipStream_t stream) {
    const float* img1 = (const float*)d_in[0];
    const float* img2 = (const float*)d_in[1];
    const int*   pos  = (const int*)d_in[2];
    float*        acc = (float*)d_ws;                     // +0
    unsigned int* cnt = (unsigned int*)((char*)d_ws + 4); // +4

    hipMemsetAsync(d_ws, 0, 8, stream);

    // 8 XCDs x 6 images x 32 strips; each block = 4 waves = 4 column strips.
    ssim_main<<<NBLK, 256, 0, stream>>>(img1, img2, pos, acc, cnt,
                                        (float*)d_out);
}

// Round 15
// 46.741 us; speedup vs baseline: 4.2000x; 1.6064x over previous
//
#include <hip/hip_runtime.h>

// Problem constants (fixed by setup_inputs).
#define B_     16
#define C_     3
#define H_     512
#define W_     1024
#define MW     256         // mask_width
#define RS     16          // output rows per strip
#define NSTRIP 32          // 32*16 = 512 exact (no ragged strip)
#define NIN    (RS + 10)   // 26 input rows streamed per strip

// Memory fence only: wave_barrier pins all DS/VMEM ordering (IR + MIR) but
// lets pure VALU flow across iterations (software pipelining).
#define FENCE() __builtin_amdgcn_wave_barrier()

__global__ __launch_bounds__(256) void ssim_main(const float* __restrict__ img1,
                                                 const float* __restrict__ img2,
                                                 const int*   __restrict__ mask_pos,
                                                 float*       __restrict__ accum) {
    // Gaussian weights = float64 exp/normalize, precomputed to float literals.
    constexpr float G[11] = {
        0.00102838f, 0.00759876f, 0.03600077f, 0.10936070f, 0.21300553f,
        0.26601173f, 0.21300553f, 0.10936070f, 0.03600077f, 0.00759876f,
        0.00102838f };

    // Per-wave double-buffered 74-col {u=x+y, v=x-y} row ring. ~5 KB total.
    __shared__ float2 rowbuf[4][2][80];
    __shared__ float  blksum[4];

    const int tid  = threadIdx.x;
    const int w    = tid >> 6;
    const int lane = tid & 63;

    // L2-locality remap: dispatch round-robins blockIdx over the 8 XCDs, so
    // give each XCD 6 complete (b,ch) images with sequential strips. Adjacent
    // strips (which share 10 halo rows) then hit the same XCD's L2.
    // Bijection: 1536 = 8 xcd * (6 images * 32 strips).
    const int d     = blockIdx.x;
    const int xcd   = d & 7;
    const int q     = d >> 3;            // 0..191 within XCD
    const int bc    = xcd * 6 + (q >> 5);// (b,ch) 0..47
    const int strip = q & 31;            // row strip 0..31
    const int b     = bc / 3;

    int s0 = mask_pos[b];
    s0 = min(max(s0, 0), W_ - MW);

    const float* __restrict__ p1 = img1 + (size_t)bc * (H_ * W_);
    const float* __restrict__ p2 = img2 + (size_t)bc * (H_ * W_);

    const int y0  = strip * RS;
    const int sx0 = w << 6;              // column strip base within crop
    const int cxm = sx0 - 5 + lane;      // main staged column (crop coords)
    const int cxh = sx0 + 59 + lane;     // halo staged column (lane < 10)
    const bool vm = (cxm >= 0) && (cxm < MW);
    const bool vh = (lane < 10) && (cxh < MW);
    const int gxm = s0 + cxm;
    const int gxh = s0 + cxh;

    // Single in-flight prefetch register set (distance 1) — RAW values only.
    // u/v transform happens AT THE STORE (bottom of iteration) so the vmcnt
    // wait stays at the ds_write, hidden under this row's compute.
    float pa0, pb0, pa1, pb1;
    auto loadrow = [&](int r) {
        pa0 = pb0 = pa1 = pb1 = 0.f;
        if (r >= 0 && r < H_) {          // wave-uniform branch
            const int ro = r * W_;
            if (vm) { pa0 = p1[ro + gxm]; pb0 = p2[ro + gxm]; }
            if (vh) { pa1 = p1[ro + gxh]; pb1 = p2[ro + gxh]; }
        }
    };

    // 11 pending output rows x 4 conv fields {mu_p, mu_m, Suu, Svv};
    // slot index `sl` is compile-time at every call site.
    float acc[11][4];
    #pragma unroll
    for (int s = 0; s < 11; ++s)
        #pragma unroll
        for (int f = 0; f < 4; ++f) acc[s][f] = 0.f;

    float psum = 0.f;
    int cur = 0;                         // runtime LDS parity (LDS, not VGPR array)

    auto dorow = [&](int i, int sl) {
        const bool notlast = (i + 1 < NIN);

        // Prefetch row i+1 into registers (hidden under this row's math).
        if (notlast) loadrow(y0 - 4 + i);

        // Horizontal 11-tap pass over 4 fields from LDS buffer `cur`.
        float su = 0.f, sv = 0.f, suu = 0.f, svv = 0.f;
        #pragma unroll
        for (int t = 0; t < 11; ++t) {
            const float2 q2 = rowbuf[w][cur][lane + t];
            const float gu = G[t] * q2.x;
            const float gv = G[t] * q2.y;
            su += gu;
            sv += gv;
            suu = fmaf(gu, q2.x, suu);
            svv = fmaf(gv, q2.y, svv);
        }

        // Vertical accumulation into the 11 pending outputs (static slots).
        #pragma unroll
        for (int m = 0; m < 11; ++m) {
            const int s = (sl + m) % 11;
            const float gw = G[10 - m];
            acc[s][0] = fmaf(gw, su,  acc[s][0]);
            acc[s][1] = fmaf(gw, sv,  acc[s][1]);
            acc[s][2] = fmaf(gw, suu, acc[s][2]);
            acc[s][3] = fmaf(gw, svv, acc[s][3]);
        }

        // Output row o = y0 + i - 10 completes in slot sl at i >= 10.
        if (i >= 10) {
            const float mup = acc[sl][0], mum = acc[sl][1];
            const float Suu = acc[sl][2], Svv = acc[sl][3];
            const float A  = mup * mup, Bq = mum * mum;
            const float mu_sq_sum = 0.5f * (A + Bq);    // mu1^2 + mu2^2
            const float mu_cross2 = 0.5f * (A - Bq);    // 2*mu1*mu2
            const float e_sum     = 0.5f * (Suu + Svv); // Exx + Eyy
            const float e_cross2  = 0.5f * (Suu - Svv); // 2*Exy
            const float sig_sum = e_sum - mu_sq_sum;    // sig1 + sig2
            const float sig12_2 = e_cross2 - mu_cross2; // 2*sig12
            const float num = (mu_cross2 + 1e-4f) * (sig12_2 + 9e-4f) + 1e-5f;
            const float den = (mu_sq_sum + 1e-4f) * (sig_sum + 9e-4f) + 1e-5f;
            psum += __fdividef(num, den);
        }
        // Slot sl recycled: always reset.
        #pragma unroll
        for (int f = 0; f < 4; ++f) acc[sl][f] = 0.f;

        // Stage prefetched row i+1: u/v computed INLINE at the store, so the
        // first use of the loads (and the vmcnt wait) is here.
        if (notlast) {
            rowbuf[w][cur ^ 1][lane] = make_float2(pa0 + pb0, pa0 - pb0);
            if (lane < 10)
                rowbuf[w][cur ^ 1][64 + lane] = make_float2(pa1 + pb1, pa1 - pb1);
        }
        cur ^= 1;
        // Memory-only fence: DS/VMEM may not cross; VALU may.
        FENCE();
    };

    // Prologue: stage streamed row 0 (input row y0-5) into parity 0.
    loadrow(y0 - 5);
    rowbuf[w][0][lane] = make_float2(pa0 + pb0, pa0 - pb0);
    if (lane < 10) rowbuf[w][0][64 + lane] = make_float2(pa1 + pb1, pa1 - pb1);
    FENCE();

    // Main 22 rows (2 x 11 so sl stays compile-time), then 4-row tail
    // (22 % 11 == 0, so tail slot == j, still compile-time).
    for (int ii = 0; ii < 22; ii += 11) {
        #pragma unroll
        for (int j = 0; j < 11; ++j) dorow(ii + j, j);
    }
    #pragma unroll
    for (int j = 0; j < 4; ++j) dorow(22 + j, j);

    // Wave reduce -> block reduce -> one atomic per block (1536 total).
    #pragma unroll
    for (int off = 32; off > 0; off >>= 1) psum += __shfl_xor(psum, off, 64);
    if (lane == 0) blksum[w] = psum;
    __syncthreads();
    if (tid == 0) {
        atomicAdd(accum, blksum[0] + blksum[1] + blksum[2] + blksum[3]);
    }
}

__global__ void ssim_final(const float* __restrict__ accum, float* __restrict__ out) {
    out[0] = 1.0f - accum[0] * (1.0f / 6291456.0f);  // B*C*H*MW = 16*3*512*256
}

extern "C" void kernel_launch(void* const* d_in, const int* in_sizes, int n_in,
                              void* d_out, int out_size, void* d_ws, size_t ws_size,
                              hipStream_t stream) {
    const float* img1 = (const float*)d_in[0];
    const float* img2 = (const float*)d_in[1];
    const int*   pos  = (const int*)d_in[2];
    float* out = (float*)d_out;
    float* acc = (float*)d_ws;

    hipMemsetAsync(acc, 0, sizeof(float), stream);

    // 8 XCDs x 6 images x 32 strips; each block = 4 waves = 4 column strips.
    ssim_main<<<B_ * C_ * NSTRIP, 256, 0, stream>>>(img1, img2, pos, acc);
    ssim_final<<<1, 1, 0, stream>>>(acc, out);
}

// Round 16
// 39.072 us; speedup vs baseline: 5.0244x; 1.1963x over previous
//
#include <hip/hip_runtime.h>

// Problem constants (fixed by setup_inputs).
#define B_     16
#define C_     3
#define H_     512
#define W_     1024
#define MW     256         // mask_width
#define RS     16          // output rows per strip
#define NSTRIP 32          // 32*16 = 512 exact (no ragged strip)
#define NIN    (RS + 10)   // 26 input rows streamed per strip
#define NBLK   (B_ * C_ * NSTRIP)  // 1536

// Memory fence only: wave_barrier pins all DS/VMEM ordering (IR + MIR) but
// lets pure VALU flow across iterations (software pipelining).
#define FENCE() __builtin_amdgcn_wave_barrier()

__global__ __launch_bounds__(256) void ssim_main(const float* __restrict__ img1,
                                                 const float* __restrict__ img2,
                                                 const int*   __restrict__ mask_pos,
                                                 float*       __restrict__ partials) {
    // Gaussian weights = float64 exp/normalize, precomputed to float literals.
    constexpr float G[11] = {
        0.00102838f, 0.00759876f, 0.03600077f, 0.10936070f, 0.21300553f,
        0.26601173f, 0.21300553f, 0.10936070f, 0.03600077f, 0.00759876f,
        0.00102838f };

    // Per-wave double-buffered 74-col {u=x+y, v=x-y} row ring. ~5 KB total.
    __shared__ float2 rowbuf[4][2][80];
    __shared__ float  blksum[4];

    const int tid  = threadIdx.x;
    const int w    = tid >> 6;
    const int lane = tid & 63;

    // L2-locality remap: dispatch round-robins blockIdx over the 8 XCDs, so
    // give each XCD 6 complete (b,ch) images with sequential strips. Adjacent
    // strips (which share 10 halo rows) then hit the same XCD's L2.
    // Bijection: 1536 = 8 xcd * (6 images * 32 strips).
    const int d     = blockIdx.x;
    const int xcd   = d & 7;
    const int q     = d >> 3;            // 0..191 within XCD
    const int bc    = xcd * 6 + (q >> 5);// (b,ch) 0..47
    const int strip = q & 31;            // row strip 0..31
    const int b     = bc / 3;

    int s0 = mask_pos[b];
    s0 = min(max(s0, 0), W_ - MW);

    const float* __restrict__ p1 = img1 + (size_t)bc * (H_ * W_);
    const float* __restrict__ p2 = img2 + (size_t)bc * (H_ * W_);

    const int y0  = strip * RS;
    const int sx0 = w << 6;              // column strip base within crop
    const int cxm = sx0 - 5 + lane;      // main staged column (crop coords)
    const int cxh = sx0 + 59 + lane;     // halo staged column (lane < 10)
    const bool vm = (cxm >= 0) && (cxm < MW);
    const bool vh = (lane < 10) && (cxh < MW);
    const int gxm = s0 + cxm;
    const int gxh = s0 + cxh;

    // Single in-flight prefetch register set (distance 1) — RAW values only.
    // u/v transform happens AT THE STORE (bottom of iteration) so the vmcnt
    // wait stays at the ds_write, hidden under this row's compute.
    float pa0, pb0, pa1, pb1;
    auto loadrow = [&](int r) {
        pa0 = pb0 = pa1 = pb1 = 0.f;
        if (r >= 0 && r < H_) {          // wave-uniform branch
            const int ro = r * W_;
            if (vm) { pa0 = p1[ro + gxm]; pb0 = p2[ro + gxm]; }
            if (vh) { pa1 = p1[ro + gxh]; pb1 = p2[ro + gxh]; }
        }
    };

    // 11 pending output rows x 4 conv fields {mu_p, mu_m, Suu, Svv};
    // slot index `sl` is compile-time at every call site. SCATTER-RMW form
    // is load-bearing for regalloc (gather form spilled, round 13).
    float acc[11][4];
    #pragma unroll
    for (int s = 0; s < 11; ++s)
        #pragma unroll
        for (int f = 0; f < 4; ++f) acc[s][f] = 0.f;

    float psum = 0.f;
    int cur = 0;                         // runtime LDS parity (LDS, not VGPR array)

    auto dorow = [&](int i, int sl) {
        const bool notlast = (i + 1 < NIN);

        // Prefetch row i+1 into registers (hidden under this row's math).
        if (notlast) loadrow(y0 - 4 + i);

        // Horizontal 11-tap pass over 4 fields from LDS buffer `cur`.
        float su = 0.f, sv = 0.f, suu = 0.f, svv = 0.f;
        #pragma unroll
        for (int t = 0; t < 11; ++t) {
            const float2 q2 = rowbuf[w][cur][lane + t];
            const float gu = G[t] * q2.x;
            const float gv = G[t] * q2.y;
            su += gu;
            sv += gv;
            suu = fmaf(gu, q2.x, suu);
            svv = fmaf(gv, q2.y, svv);
        }

        // Vertical accumulation into the 11 pending outputs (static slots).
        #pragma unroll
        for (int m = 0; m < 11; ++m) {
            const int s = (sl + m) % 11;
            const float gw = G[10 - m];
            acc[s][0] = fmaf(gw, su,  acc[s][0]);
            acc[s][1] = fmaf(gw, sv,  acc[s][1]);
            acc[s][2] = fmaf(gw, suu, acc[s][2]);
            acc[s][3] = fmaf(gw, svv, acc[s][3]);
        }

        // Output row o = y0 + i - 10 completes in slot sl at i >= 10.
        if (i >= 10) {
            const float mup = acc[sl][0], mum = acc[sl][1];
            const float Suu = acc[sl][2], Svv = acc[sl][3];
            const float A  = mup * mup, Bq = mum * mum;
            const float mu_sq_sum = 0.5f * (A + Bq);    // mu1^2 + mu2^2
            const float mu_cross2 = 0.5f * (A - Bq);    // 2*mu1*mu2
            const float e_sum     = 0.5f * (Suu + Svv); // Exx + Eyy
            const float e_cross2  = 0.5f * (Suu - Svv); // 2*Exy
            const float sig_sum = e_sum - mu_sq_sum;    // sig1 + sig2
            const float sig12_2 = e_cross2 - mu_cross2; // 2*sig12
            const float num = (mu_cross2 + 1e-4f) * (sig12_2 + 9e-4f) + 1e-5f;
            const float den = (mu_sq_sum + 1e-4f) * (sig_sum + 9e-4f) + 1e-5f;
            psum += __fdividef(num, den);
        }
        // Slot sl recycled: always reset.
        #pragma unroll
        for (int f = 0; f < 4; ++f) acc[sl][f] = 0.f;

        // Stage prefetched row i+1: u/v computed INLINE at the store, so the
        // first use of the loads (and the vmcnt wait) is here.
        if (notlast) {
            rowbuf[w][cur ^ 1][lane] = make_float2(pa0 + pb0, pa0 - pb0);
            if (lane < 10)
                rowbuf[w][cur ^ 1][64 + lane] = make_float2(pa1 + pb1, pa1 - pb1);
        }
        cur ^= 1;
        // Memory-only fence: DS/VMEM may not cross; VALU may.
        FENCE();
    };

    // Prologue: stage streamed row 0 (input row y0-5) into parity 0.
    loadrow(y0 - 5);
    rowbuf[w][0][lane] = make_float2(pa0 + pb0, pa0 - pb0);
    if (lane < 10) rowbuf[w][0][64 + lane] = make_float2(pa1 + pb1, pa1 - pb1);
    FENCE();

    // Main 22 rows (2 x 11 so sl stays compile-time), then 4-row tail
    // (22 % 11 == 0, so tail slot == j, still compile-time).
    for (int ii = 0; ii < 22; ii += 11) {
        #pragma unroll
        for (int j = 0; j < 11; ++j) dorow(ii + j, j);
    }
    #pragma unroll
    for (int j = 0; j < 4; ++j) dorow(22 + j, j);

    // Wave reduce -> block reduce -> ONE PLAIN STORE per block (no atomic,
    // no accumulator zeroing needed: every slot written every run).
    #pragma unroll
    for (int off = 32; off > 0; off >>= 1) psum += __shfl_xor(psum, off, 64);
    if (lane == 0) blksum[w] = psum;
    __syncthreads();
    if (tid == 0) {
        partials[d] = blksum[0] + blksum[1] + blksum[2] + blksum[3];
    }
}

__global__ __launch_bounds__(256) void ssim_final(const float* __restrict__ partials,
                                                  float* __restrict__ out) {
    __shared__ float red[4];
    const int t = threadIdx.x;
    float s = 0.f;
    #pragma unroll
    for (int k = 0; k < NBLK / 256; ++k) s += partials[t + 256 * k];
    #pragma unroll
    for (int off = 32; off > 0; off >>= 1) s += __shfl_xor(s, off, 64);
    if ((t & 63) == 0) red[t >> 6] = s;
    __syncthreads();
    if (t == 0)
        out[0] = 1.0f - (red[0] + red[1] + red[2] + red[3]) * (1.0f / 6291456.0f);
}

extern "C" void kernel_launch(void* const* d_in, const int* in_sizes, int n_in,
                              void* d_out, int out_size, void* d_ws, size_t ws_size,
                              hipStream_t stream) {
    const float* img1 = (const float*)d_in[0];
    const float* img2 = (const float*)d_in[1];
    const int*   pos  = (const int*)d_in[2];
    float* out      = (float*)d_out;
    float* partials = (float*)d_ws;      // NBLK floats = 6 KB scratch

    // No memset: every partials slot is unconditionally written by ssim_main.
    // 8 XCDs x 6 images x 32 strips; each block = 4 waves = 4 column strips.
    ssim_main<<<NBLK, 256, 0, stream>>>(img1, img2, pos, partials);
    ssim_final<<<1, 256, 0, stream>>>(partials, out);
}